// Round 4
// baseline (1294.945 us; speedup 1.0000x reference)
//
#include <hip/hip_runtime.h>
#include <stdint.h>

#define DEV static __device__ __forceinline__

constexpr int B = 4096, D = 256, H = 2048, O = 256;

typedef __bf16 bf16x8 __attribute__((ext_vector_type(8)));
typedef float f32x4 __attribute__((ext_vector_type(4)));
typedef unsigned short u16x8 __attribute__((ext_vector_type(8)));

DEV unsigned short f2bf(float f) {
    uint32_t u = __builtin_bit_cast(uint32_t, f);
    u += 0x7FFF + ((u >> 16) & 1);          // RNE
    return (unsigned short)(u >> 16);
}
DEV float bf2f(unsigned short s) { return __builtin_bit_cast(float, (uint32_t)s << 16); }

DEV u16x8 cvt8(float4 a, float4 b) {
    u16x8 v;
    v[0] = f2bf(a.x); v[1] = f2bf(a.y); v[2] = f2bf(a.z); v[3] = f2bf(a.w);
    v[4] = f2bf(b.x); v[5] = f2bf(b.y); v[6] = f2bf(b.z); v[7] = f2bf(b.w);
    return v;
}

// ---------------- weight transpose+convert ----------------
// in: [E][K][N] f32  ->  out: [E][N][K] bf16
__global__ void k_trcvt(const float* __restrict__ in, unsigned short* __restrict__ out,
                        int K, int N) {
    __shared__ float tl[32][33];
    size_t eoff = (size_t)blockIdx.z * K * N;
    in += eoff; out += eoff;
    int n0 = blockIdx.x * 32, k0 = blockIdx.y * 32;
    int tx = threadIdx.x, ty = threadIdx.y;     // block (32,8)
#pragma unroll
    for (int i = 0; i < 4; i++)
        tl[ty + i * 8][tx] = in[(size_t)(k0 + ty + i * 8) * N + n0 + tx];
    __syncthreads();
#pragma unroll
    for (int i = 0; i < 4; i++)
        out[(size_t)(n0 + ty + i * 8) * K + k0 + tx] = f2bf(tl[tx][ty + i * 8]);
}

// ---------------- expert GEMM: hidden = relu(x @ W + b) ----------------
// 18 problems: p<8 task (K=256) -> te (bf16, ws); p>=8 shared -> se (f32, d_out)

__launch_bounds__(256, 2)
__global__ void k_expert(const float* x0, const float* x1, const float* x2, const float* x3,
                         const float* x4, const float* x5, const float* x6, const float* x7,
                         const unsigned short* __restrict__ WtT,
                         const unsigned short* __restrict__ WtB2,
                         const unsigned short* __restrict__ WtB3,
                         const float* __restrict__ b_task,
                         const float* __restrict__ b_b2,
                         const float* __restrict__ b_b3,
                         unsigned short* __restrict__ te,
                         float* __restrict__ se_f) {
    __shared__ __align__(16) unsigned short As[128 * 64];
    __shared__ __align__(16) unsigned short Bs[128 * 64];

    int bx = blockIdx.x;
    int p = bx >> 9;            // 512 tiles per problem (32 m x 16 n)
    int rem = bx & 511;
    int mt = rem >> 4, nt = rem & 15;

    int K;
    const unsigned short* Wt; const float* bias;
    unsigned short* dst_bf = nullptr; float* dst_f = nullptr;
    const float *xa, *xbp, *xc;
    if (p < 8) {
        K = 256;
        Wt = WtT + (size_t)p * H * 256; bias = b_task + p * H; dst_bf = te + (size_t)p * B * H;
        switch (p) {
            case 0: xa = x0; break; case 1: xa = x1; break; case 2: xa = x2; break; case 3: xa = x3; break;
            case 4: xa = x4; break; case 5: xa = x5; break; case 6: xa = x6; break; default: xa = x7;
        }
        xbp = xa; xc = xa;
    } else if (p < 12) {
        int e = p - 8; K = 512;
        Wt = WtB2 + (size_t)e * H * 512; bias = b_b2 + e * H; dst_f = se_f + (size_t)e * B * H;
        xa = x2; xbp = x3; xc = x3;
    } else {
        int e = p - 12; K = 768;
        Wt = WtB3 + (size_t)e * H * 768; bias = b_b3 + e * H; dst_f = se_f + (size_t)(4 + e) * B * H;
        xa = x5; xbp = x6; xc = x7;
    }

    int tid = threadIdx.x;
    int lane = tid & 63, wv = tid >> 6;
    int wr = wv >> 1, wc = wv & 1;
    int lrow = lane & 15, lk = lane >> 4;
    int mrow0 = mt * 128, ncol0 = nt * 128;

    f32x4 acc[4][4] = {};

    int nseg = K >> 8;
    for (int seg = 0; seg < nseg; ++seg) {
        const float* xp = (seg == 0) ? xa : ((seg == 1) ? xbp : xc);
#pragma unroll 1
        for (int kk = 0; kk < 4; ++kk) {
            int kt = (seg << 8) + (kk << 6);
            // ---- global -> regs ----
            float4 ar0[4], ar1[4];
            u16x8 bvr[4];
#pragma unroll
            for (int r = 0; r < 4; r++) {
                int idx = r * 256 + tid;
                int row = idx >> 3, fo = (idx & 7) * 8;
                const float* s = xp + (size_t)(mrow0 + row) * D + (kk << 6) + fo;
                ar0[r] = *(const float4*)s;
                ar1[r] = *(const float4*)(s + 4);
            }
#pragma unroll
            for (int r = 0; r < 4; r++) {
                int idx = r * 256 + tid;
                int row = idx >> 3, ko = (idx & 7) * 8;
                bvr[r] = *(const u16x8*)(Wt + (size_t)(ncol0 + row) * K + kt + ko);
            }
            __syncthreads();    // previous iteration's LDS reads complete
            // ---- regs -> LDS ----
#pragma unroll
            for (int r = 0; r < 4; r++) {
                int idx = r * 256 + tid;
                *(u16x8*)&As[idx * 8] = cvt8(ar0[r], ar1[r]);
                *(u16x8*)&Bs[idx * 8] = bvr[r];
            }
            __syncthreads();
            // ---- MFMA ----
#pragma unroll
            for (int ks = 0; ks < 2; ks++) {
                bf16x8 af[4], bfv[4];
#pragma unroll
                for (int m = 0; m < 4; m++)
                    af[m] = *reinterpret_cast<const bf16x8*>(&As[(wr * 64 + m * 16 + lrow) * 64 + ks * 32 + lk * 8]);
#pragma unroll
                for (int n = 0; n < 4; n++)
                    bfv[n] = *reinterpret_cast<const bf16x8*>(&Bs[(wc * 64 + n * 16 + lrow) * 64 + ks * 32 + lk * 8]);
#pragma unroll
                for (int m = 0; m < 4; m++)
#pragma unroll
                    for (int n = 0; n < 4; n++)
                        acc[m][n] = __builtin_amdgcn_mfma_f32_16x16x32_bf16(af[m], bfv[n], acc[m][n], 0, 0, 0);
            }
        }
    }

#pragma unroll
    for (int n = 0; n < 4; n++) {
        int col = ncol0 + wc * 64 + n * 16 + lrow;
        float bv = bias[col];
#pragma unroll
        for (int m = 0; m < 4; m++) {
            int rbase = mrow0 + wr * 64 + m * 16 + lk * 4;
#pragma unroll
            for (int r = 0; r < 4; r++) {
                float v = fmaxf(acc[m][n][r] + bv, 0.f);
                if (dst_bf) dst_bf[(size_t)(rbase + r) * H + col] = f2bf(v);
                else        dst_f [(size_t)(rbase + r) * H + col] = v;
            }
        }
    }
}

// ---------------- gates ----------------
// rows [0, 8B): task gates  sigmoid(x_t . Wg_task[t] + bg)
// rows [8B, 18B): shared gates sigmoid(se_e . Wg + bg), e in 0..9 (b2 then b3)

__global__ void k_gates(const float* x0, const float* x1, const float* x2, const float* x3,
                        const float* x4, const float* x5, const float* x6, const float* x7,
                        const float* __restrict__ Wg_task, const float* __restrict__ bg_task,
                        const float* __restrict__ Wg_b2, const float* __restrict__ bg_b2,
                        const float* __restrict__ Wg_b3, const float* __restrict__ bg_b3,
                        const float* __restrict__ se_f, float* __restrict__ g) {
    int rid = blockIdx.x * 4 + (threadIdx.x >> 6);
    int lane = threadIdx.x & 63;
    float s = 0.f, bgv;
    if (rid < 8 * B) {
        int t = rid >> 12, b = rid & 4095;
        const float* xs;
        switch (t) {
            case 0: xs = x0; break; case 1: xs = x1; break; case 2: xs = x2; break; case 3: xs = x3; break;
            case 4: xs = x4; break; case 5: xs = x5; break; case 6: xs = x6; break; default: xs = x7;
        }
        float4 xv = *(const float4*)(xs + (size_t)b * D + lane * 4);
        float4 wv = *(const float4*)(Wg_task + t * D + lane * 4);
        s = xv.x * wv.x + xv.y * wv.y + xv.z * wv.z + xv.w * wv.w;
        bgv = bg_task[t];
    } else {
        int r2 = rid - 8 * B;
        int e = r2 >> 12, b = r2 & 4095;
        const float* ar = se_f + (size_t)e * B * H + (size_t)b * H + lane * 32;
        const float* wr = ((e < 4) ? (Wg_b2 + (size_t)e * H) : (Wg_b3 + (size_t)(e - 4) * H)) + lane * 32;
#pragma unroll
        for (int i = 0; i < 8; i++) {
            float4 av = *(const float4*)(ar + i * 4);
            float4 wv = *(const float4*)(wr + i * 4);
            s += av.x * wv.x + av.y * wv.y + av.z * wv.z + av.w * wv.w;
        }
        bgv = (e < 4) ? bg_b2[e] : bg_b3[e - 4];
    }
#pragma unroll
    for (int o = 32; o; o >>= 1) s += __shfl_down(s, o);
    if (lane == 0) g[rid] = 1.f / (1.f + __expf(-(s + bgv)));
}

// ---------------- head GEMM with routing ----------------
// per task t: out[t] = sum over contributions c of g_c[row]*(A_c @ Wo_c) + bo_c

__launch_bounds__(256, 2)
__global__ void k_head(const unsigned short* __restrict__ te,
                       const float* __restrict__ se_f,
                       const unsigned short* __restrict__ WotT,
                       const unsigned short* __restrict__ WotB2,
                       const unsigned short* __restrict__ WotB3,
                       const float* __restrict__ g,
                       const float* __restrict__ bo_task,
                       const float* __restrict__ bo_b2,
                       const float* __restrict__ bo_b3,
                       float* __restrict__ out) {
    __shared__ __align__(16) unsigned short As[128 * 64];
    __shared__ __align__(16) unsigned short Bs[128 * 64];

    int bx = blockIdx.x;
    int t = bx >> 6;            // 64 tiles per task (32 m x 2 n)
    int rem = bx & 63;
    int mt = rem >> 1, ntc = rem & 1;

    int tid = threadIdx.x;
    int lane = tid & 63, wv = tid >> 6;
    int wr = wv >> 1, wc = wv & 1;
    int lrow = lane & 15, lk = lane >> 4;
    int mrow0 = mt * 128, ncol0 = ntc * 128;

    int nc = (t == 0) ? 1 : ((t == 1) ? 3 : ((t == 4) ? 4 : 2));

    float tot[4][4][4] = {};

#pragma unroll 1
    for (int ci = 0; ci < nc; ci++) {
        const unsigned short* Abf = nullptr; const float* Af = nullptr;
        const unsigned short* W; const float *gpn, *bo;
        if (ci == 0) {
            Abf = te + (size_t)t * B * H; W = WotT + (size_t)t * O * H;
            gpn = g + (size_t)t * B; bo = bo_task + t * O;
        } else if (t <= 3) {
            int e = (t == 1) ? (ci - 1) : t;
            Af = se_f + (size_t)e * B * H; W = WotB2 + (size_t)e * O * H;
            gpn = g + (size_t)(8 + e) * B; bo = bo_b2 + e * O;
        } else {
            int e = (t == 4) ? (ci - 1) : (t - 2);
            Af = se_f + (size_t)(4 + e) * B * H; W = WotB3 + (size_t)e * O * H;
            gpn = g + (size_t)(12 + e) * B; bo = bo_b3 + e * O;
        }

        f32x4 acc[4][4] = {};
#pragma unroll 1
        for (int kt = 0; kt < H; kt += 64) {
            u16x8 avr[4], bvr[4];
#pragma unroll
            for (int r = 0; r < 4; r++) {
                int idx = r * 256 + tid;
                int row = idx >> 3, ko = (idx & 7) * 8;
                if (Abf) {
                    avr[r] = *(const u16x8*)(Abf + (size_t)(mrow0 + row) * H + kt + ko);
                } else {
                    const float* s = Af + (size_t)(mrow0 + row) * H + kt + ko;
                    avr[r] = cvt8(*(const float4*)s, *(const float4*)(s + 4));
                }
                bvr[r] = *(const u16x8*)(W + (size_t)(ncol0 + row) * H + kt + ko);
            }
            __syncthreads();
#pragma unroll
            for (int r = 0; r < 4; r++) {
                int idx = r * 256 + tid;
                *(u16x8*)&As[idx * 8] = avr[r];
                *(u16x8*)&Bs[idx * 8] = bvr[r];
            }
            __syncthreads();
#pragma unroll
            for (int ks = 0; ks < 2; ks++) {
                bf16x8 af[4], bfv[4];
#pragma unroll
                for (int m = 0; m < 4; m++)
                    af[m] = *reinterpret_cast<const bf16x8*>(&As[(wr * 64 + m * 16 + lrow) * 64 + ks * 32 + lk * 8]);
#pragma unroll
                for (int n = 0; n < 4; n++)
                    bfv[n] = *reinterpret_cast<const bf16x8*>(&Bs[(wc * 64 + n * 16 + lrow) * 64 + ks * 32 + lk * 8]);
#pragma unroll
                for (int m = 0; m < 4; m++)
#pragma unroll
                    for (int n = 0; n < 4; n++)
                        acc[m][n] = __builtin_amdgcn_mfma_f32_16x16x32_bf16(af[m], bfv[n], acc[m][n], 0, 0, 0);
            }
        }

        float4 gvm[4];
#pragma unroll
        for (int m = 0; m < 4; m++) {
            int rbase = mrow0 + wr * 64 + m * 16 + lk * 4;
            gvm[m] = *(const float4*)(gpn + rbase);
        }
#pragma unroll
        for (int n = 0; n < 4; n++) {
            int col = ncol0 + wc * 64 + n * 16 + lrow;
            float bv = bo[col];
#pragma unroll
            for (int m = 0; m < 4; m++) {
                tot[m][n][0] += gvm[m].x * acc[m][n][0] + bv;
                tot[m][n][1] += gvm[m].y * acc[m][n][1] + bv;
                tot[m][n][2] += gvm[m].z * acc[m][n][2] + bv;
                tot[m][n][3] += gvm[m].w * acc[m][n][3] + bv;
            }
        }
    }

    size_t obase = (size_t)t * B * O;
#pragma unroll
    for (int n = 0; n < 4; n++) {
        int col = ncol0 + wc * 64 + n * 16 + lrow;
#pragma unroll
        for (int m = 0; m < 4; m++) {
            int rbase = mrow0 + wr * 64 + m * 16 + lk * 4;
#pragma unroll
            for (int r = 0; r < 4; r++)
                out[obase + (size_t)(rbase + r) * O + col] = tot[m][n][r];
        }
    }
}

// ---------------- launcher ----------------

extern "C" void kernel_launch(void* const* d_in, const int* in_sizes, int n_in,
                              void* d_out, int out_size, void* d_ws, size_t ws_size,
                              hipStream_t stream) {
    (void)in_sizes; (void)n_in; (void)out_size; (void)ws_size;
    const float* x[8];
    for (int i = 0; i < 8; i++) x[i] = (const float*)d_in[i];
    const float* W_task  = (const float*)d_in[8];
    const float* b_task  = (const float*)d_in[9];
    const float* Wg_task = (const float*)d_in[10];
    const float* bg_task = (const float*)d_in[11];
    const float* Wo_task = (const float*)d_in[12];
    const float* bo_task = (const float*)d_in[13];
    const float* W_b2    = (const float*)d_in[14];
    const float* b_b2    = (const float*)d_in[15];
    const float* Wg_b2   = (const float*)d_in[16];
    const float* bg_b2   = (const float*)d_in[17];
    const float* Wo_b2   = (const float*)d_in[18];
    const float* bo_b2   = (const float*)d_in[19];
    const float* W_b3    = (const float*)d_in[20];
    const float* b_b3    = (const float*)d_in[21];
    const float* Wg_b3   = (const float*)d_in[22];
    const float* bg_b3   = (const float*)d_in[23];
    const float* Wo_b3   = (const float*)d_in[24];
    const float* bo_b3   = (const float*)d_in[25];

    float* out = (float*)d_out;                      // f32 outputs!
    float* se_f = out + (size_t)8 * B * O;           // se2 then se3 region of d_out (f32)

    char* ws = (char*)d_ws;
    // ws layout (bytes):
    unsigned short* WtT   = (unsigned short*)(ws);               //  8*2048*256*2  =  8388608
    unsigned short* WtB2  = (unsigned short*)(ws + 8388608);     //  4*2048*512*2  =  8388608
    unsigned short* WtB3  = (unsigned short*)(ws + 16777216);    //  6*2048*768*2  = 18874368
    unsigned short* WotT  = (unsigned short*)(ws + 35651584);    //  8*2048*256*2  =  8388608
    unsigned short* WotB2 = (unsigned short*)(ws + 44040192);    //  4*2048*256*2  =  4194304
    unsigned short* WotB3 = (unsigned short*)(ws + 48234496);    //  6*2048*256*2  =  6291456
    unsigned short* te    = (unsigned short*)(ws + 54525952);    //  8*4096*2048*2 = 134217728
    float* g              = (float*)(ws + 188743680);            //  18*4096*4     =   294912
                                                                 //  total 189038592 B (~180 MiB)

    k_trcvt<<<dim3(H / 32, D / 32, 8),   dim3(32, 8), 0, stream>>>(W_task, WtT, D, H);
    k_trcvt<<<dim3(H / 32, 512 / 32, 4), dim3(32, 8), 0, stream>>>(W_b2, WtB2, 512, H);
    k_trcvt<<<dim3(H / 32, 768 / 32, 6), dim3(32, 8), 0, stream>>>(W_b3, WtB3, 768, H);
    k_trcvt<<<dim3(O / 32, H / 32, 8),   dim3(32, 8), 0, stream>>>(Wo_task, WotT, H, O);
    k_trcvt<<<dim3(O / 32, H / 32, 4),   dim3(32, 8), 0, stream>>>(Wo_b2, WotB2, H, O);
    k_trcvt<<<dim3(O / 32, H / 32, 6),   dim3(32, 8), 0, stream>>>(Wo_b3, WotB3, H, O);

    k_expert<<<dim3(18 * 512), 256, 0, stream>>>(x[0], x[1], x[2], x[3], x[4], x[5], x[6], x[7],
                                                 WtT, WtB2, WtB3, b_task, b_b2, b_b3, te, se_f);

    k_gates<<<dim3(18 * B / 4), 256, 0, stream>>>(x[0], x[1], x[2], x[3], x[4], x[5], x[6], x[7],
                                                  Wg_task, bg_task, Wg_b2, bg_b2, Wg_b3, bg_b3, se_f, g);

    k_head<<<dim3(8 * 64), 256, 0, stream>>>(te, se_f, WotT, WotB2, WotB3, g,
                                             bo_task, bo_b2, bo_b3, out);
}